// Round 8
// baseline (1536.824 us; speedup 1.0000x reference)
//
#include <hip/hip_runtime.h>
#include <hip/hip_bf16.h>
#include <cstdint>

#define NN 256
#define NB 4
#define OC 128
#define GRID 1024

using bf16x8_t = __attribute__((ext_vector_type(8))) __bf16;
using f32x4_t  = __attribute__((ext_vector_type(4))) float;

typedef const __attribute__((address_space(1))) uint8_t* gptr1_t;
typedef __attribute__((address_space(3))) uint8_t* lptr3_t;

__device__ __forceinline__ void async_load16(const void* g, void* l) {
  __builtin_amdgcn_global_load_lds((gptr1_t)g, (lptr3_t)l, 16, 0, 0);
}

__device__ __forceinline__ float sigf(float x) {
  return __builtin_amdgcn_rcpf(1.0f + __expf(-x));
}

__device__ __forceinline__ uint16_t f2bf_rne(float f) {
  uint32_t u = __float_as_uint(f);
  uint32_t r = (u + 0x7fffu + ((u >> 16) & 1u)) >> 16;
  return (uint16_t)r;
}

// ---- grid-wide sync primitives (1024 co-resident blocks guaranteed by
// launch_bounds(256,4): LDS 36.8KB -> 4/CU, VGPR<=128 -> 4 waves/SIMD) ----
struct Ctrs { unsigned ctr, gen, done0, done1, done2; };

__device__ __forceinline__ void gbar(Ctrs* C, int tid) {
  __syncthreads();
  if (tid == 0) {
    __threadfence();  // block's writes visible device-wide before arriving
    unsigned g = __hip_atomic_load(&C->gen, __ATOMIC_RELAXED,
                                   __HIP_MEMORY_SCOPE_AGENT);
    unsigned a = __hip_atomic_fetch_add(&C->ctr, 1u, __ATOMIC_ACQ_REL,
                                        __HIP_MEMORY_SCOPE_AGENT);
    if (a == GRID - 1) {
      __hip_atomic_store(&C->ctr, 0u, __ATOMIC_RELAXED,
                         __HIP_MEMORY_SCOPE_AGENT);
      __hip_atomic_fetch_add(&C->gen, 1u, __ATOMIC_RELEASE,
                             __HIP_MEMORY_SCOPE_AGENT);
    } else {
      while (__hip_atomic_load(&C->gen, __ATOMIC_ACQUIRE,
                               __HIP_MEMORY_SCOPE_AGENT) == g)
        __builtin_amdgcn_s_sleep(8);
    }
    __threadfence();
  }
  __syncthreads();
  __builtin_amdgcn_fence(__ATOMIC_ACQUIRE, "agent");
}

__device__ __forceinline__ void mark_done(unsigned* d, int tid) {
  __syncthreads();
  __builtin_amdgcn_fence(__ATOMIC_RELEASE, "agent");
  if (tid == 0)
    __hip_atomic_fetch_add(d, 1u, __ATOMIC_RELAXED, __HIP_MEMORY_SCOPE_AGENT);
}

__device__ __forceinline__ void wait_done(unsigned* d, int tid) {
  if (tid == 0) {
    while (__hip_atomic_load(d, __ATOMIC_RELAXED, __HIP_MEMORY_SCOPE_AGENT) <
           52u)
      __builtin_amdgcn_s_sleep(8);
  }
  __syncthreads();
  __builtin_amdgcn_fence(__ATOMIC_ACQUIRE, "agent");
}

// ---------------------------------------------------------------------------
// prep unit (weights transpose/pack, g1bf0 static slots, r2 init)
// ---------------------------------------------------------------------------
__device__ __forceinline__ void emit_wt(const float* __restrict__ W2,
                                        uint16_t* __restrict__ Wt, int d1,
                                        int d2, int idx) {
  const int K = 2 * d2;
  const int nn = idx / K, k = idx - nn * K;
  const int row = (k < d2) ? (d1 + k) : (2 * d1 + d2 + (k - d2));
  Wt[idx] = f2bf_rne(W2[row * OC + nn]);
}

__device__ __forceinline__ void emit_bt(const float* __restrict__ W1,
                                        const float* __restrict__ W2,
                                        uint16_t* __restrict__ Bt, int D0,
                                        int D1, int D2, int FIN1, int KP,
                                        int idx) {
  const int n = idx / KP, k = idx - n * KP;
  float val = 0.f;
  if (n < 128) {
    if (k < FIN1) val = W1[k * OC + n];
  } else if (n < 256) {
    if (k >= D0 && k < D0 + D1) val = W2[(k - D0) * OC + (n - 128)];
  } else {
    if (k >= D0 && k < D0 + D1) val = W2[(D1 + D2 + (k - D0)) * OC + (n - 256)];
  }
  Bt[idx] = f2bf_rne(val);
}

__device__ void prep_unit(
    int g, const float* W2_0, const float* W2_1, const float* W2_2,
    const float* W1_0, const float* W1_1, const float* W1_2, const float* x0,
    const float* x1, uint16_t* Wt0, uint16_t* Wt1, uint16_t* Wt2,
    uint16_t* Bt0, uint16_t* Bt1, uint16_t* Bt2, uint16_t* g1bf0, float* r2b,
    float* r2c) {
  if (g < 16384) { emit_wt(W2_0, Wt0, 64, 64, g); return; }
  g -= 16384;
  if (g < 32768) { emit_wt(W2_1, Wt1, 128, 128, g); return; }
  g -= 32768;
  if (g < 32768) { emit_wt(W2_2, Wt2, 128, 128, g); return; }
  g -= 32768;
  if (g < 98304) { emit_bt(W1_0, W2_0, Bt0, 32, 64, 64, 224, 256, g); return; }
  g -= 98304;
  if (g < 196608) { emit_bt(W1_1, W2_1, Bt1, 128, 128, 128, 512, 512, g); return; }
  g -= 196608;
  if (g < 196608) { emit_bt(W1_2, W2_2, Bt2, 128, 128, 128, 512, 512, g); return; }
  g -= 196608;
  if (g < 131072) {  // g1bf0 static slots: f0[0..32) f1[32..96) pad[224..256)
    const int row = g >> 7, t = g & 127;
    uint16_t* const gp = g1bf0 + (size_t)row * 256;
    if (t < 32) gp[t] = f2bf_rne(x0[(row >> 8) * 32 + t]);
    else if (t < 96) gp[t] = f2bf_rne(x1[(size_t)row * 64 + (t - 32)]);
    else gp[128 + t] = 0;
    return;
  }
  g -= 131072;
  if (g < 262144) { r2b[g] = ((g & 255) < 128) ? 0.f : 1.f; return; }
  g -= 262144;
  if (g < 262144) { r2c[g] = ((g & 255) < 128) ? 0.f : 1.f; }
}

// ---------------------------------------------------------------------------
// reduce2 layer 0 unit: fp32 x2 -> bf16 x2bf + max/min into g1bf0
// ---------------------------------------------------------------------------
__device__ void reduce2_unit(int bid, const float* __restrict__ x2,
                             uint16_t* __restrict__ g1bf0,
                             uint16_t* __restrict__ x2bf, uint8_t* ldsraw,
                             int tid) {
  float4* const smx = (float4*)ldsraw;
  float4* const smn = (float4*)(ldsraw + 4096);
  const int i = bid & 255;
  const int q = tid & 15, s = tid >> 4;
  const size_t rowbase = ((size_t)bid * NN) * 64 + q * 4;
  float mxA0 = 0.f, mxA1 = 0.f, mxA2 = 0.f, mxA3 = 0.f;
  float mnA0 = 1.f, mnA1 = 1.f, mnA2 = 1.f, mnA3 = 1.f;
  float mxB0 = 0.f, mxB1 = 0.f, mxB2 = 0.f, mxB3 = 0.f;
  float mnB0 = 1.f, mnB1 = 1.f, mnB2 = 1.f, mnB3 = 1.f;
#pragma unroll 2
  for (int t = 0; t < 16; t += 2) {
    const int jA = s + t * 16, jB = jA + 16;
    const float4 xa = *(const float4*)(x2 + rowbase + (size_t)jA * 64);
    const float4 xb = *(const float4*)(x2 + rowbase + (size_t)jB * 64);
    uint2 pa, pb;
    pa.x = (uint32_t)f2bf_rne(xa.x) | ((uint32_t)f2bf_rne(xa.y) << 16);
    pa.y = (uint32_t)f2bf_rne(xa.z) | ((uint32_t)f2bf_rne(xa.w) << 16);
    pb.x = (uint32_t)f2bf_rne(xb.x) | ((uint32_t)f2bf_rne(xb.y) << 16);
    pb.y = (uint32_t)f2bf_rne(xb.z) | ((uint32_t)f2bf_rne(xb.w) << 16);
    *(uint2*)(x2bf + rowbase + (size_t)jA * 64) = pa;
    *(uint2*)(x2bf + rowbase + (size_t)jB * 64) = pb;
    if (jA != i) {
      mxA0 = fmaxf(mxA0, xa.x); mxA1 = fmaxf(mxA1, xa.y);
      mxA2 = fmaxf(mxA2, xa.z); mxA3 = fmaxf(mxA3, xa.w);
      mnA0 = fminf(mnA0, xa.x); mnA1 = fminf(mnA1, xa.y);
      mnA2 = fminf(mnA2, xa.z); mnA3 = fminf(mnA3, xa.w);
    }
    if (jB != i) {
      mxB0 = fmaxf(mxB0, xb.x); mxB1 = fmaxf(mxB1, xb.y);
      mxB2 = fmaxf(mxB2, xb.z); mxB3 = fmaxf(mxB3, xb.w);
      mnB0 = fminf(mnB0, xb.x); mnB1 = fminf(mnB1, xb.y);
      mnB2 = fminf(mnB2, xb.z); mnB3 = fminf(mnB3, xb.w);
    }
  }
  float mx0 = fmaxf(mxA0, mxB0), mx1 = fmaxf(mxA1, mxB1);
  float mx2 = fmaxf(mxA2, mxB2), mx3 = fmaxf(mxA3, mxB3);
  float mn0 = fminf(mnA0, mnB0), mn1 = fminf(mnA1, mnB1);
  float mn2 = fminf(mnA2, mnB2), mn3 = fminf(mnA3, mnB3);
  smx[tid] = make_float4(mx0, mx1, mx2, mx3);
  smn[tid] = make_float4(mn0, mn1, mn2, mn3);
  __syncthreads();
  if (s == 0) {
    for (int ss = 1; ss < 16; ++ss) {
      float4 a = smx[q + ss * 16], c = smn[q + ss * 16];
      mx0 = fmaxf(mx0, a.x); mx1 = fmaxf(mx1, a.y);
      mx2 = fmaxf(mx2, a.z); mx3 = fmaxf(mx3, a.w);
      mn0 = fminf(mn0, c.x); mn1 = fminf(mn1, c.y);
      mn2 = fminf(mn2, c.z); mn3 = fminf(mn3, c.w);
    }
    uint16_t* const g = g1bf0 + (size_t)bid * 256;
    g[96 + q * 4 + 0] = f2bf_rne(mx0); g[96 + q * 4 + 1] = f2bf_rne(mx1);
    g[96 + q * 4 + 2] = f2bf_rne(mx2); g[96 + q * 4 + 3] = f2bf_rne(mx3);
    g[160 + q * 4 + 0] = f2bf_rne(mn0); g[160 + q * 4 + 1] = f2bf_rne(mn1);
    g[160 + q * 4 + 2] = f2bf_rne(mn2); g[160 + q * 4 + 3] = f2bf_rne(mn3);
  }
}

// ---------------------------------------------------------------------------
// Small fused MFMA GEMM + o0 (R7 proven body as device function).
// ---------------------------------------------------------------------------
template <int KP, int D0, int D1, bool DUP, bool R2FUSE>
__device__ void sg_body(int bid, const uint16_t* __restrict__ g1,
                        const uint16_t* __restrict__ Bt,
                        const float* __restrict__ b1,
                        const float* __restrict__ b2, float* __restrict__ f1out,
                        uint16_t* __restrict__ g1next, float* __restrict__ u,
                        float* __restrict__ vT, const float* __restrict__ f0in,
                        const float* __restrict__ f1in,
                        const float* __restrict__ W0,
                        const float* __restrict__ b0,
                        float* __restrict__ f0out,
                        const float* __restrict__ r2src, uint8_t* ldsA,
                        uint8_t* ldsB, int tid) {
  constexpr int NCH = KP / 64;
  if (bid < 48) {
    const int mt = bid / 3, nt = bid - mt * 3;
    const int m0 = mt * 64, n0 = nt * 128;
    const int wv = tid >> 6, lane = tid & 63;
    const int l15 = lane & 15, l4 = lane >> 4;

    f32x4_t acc[4][2];
#pragma unroll
    for (int a = 0; a < 4; ++a)
#pragma unroll
      for (int q = 0; q < 2; ++q) acc[a][q] = (f32x4_t){0.f, 0.f, 0.f, 0.f};

    for (int c = 0; c < NCH; ++c) {
      const int kbg = c * 64;
#pragma unroll
      for (int t = 0; t < 2; ++t) {  // A units: id = ks*4 + mi
        const int id = wv * 2 + t;
        const int mi = id & 3, ks = id >> 2;
        if (R2FUSE && kbg >= KP / 2) {
          const float* const src = r2src +
              (size_t)(m0 + mi * 16 + l15) * (KP / 2) + (kbg - KP / 2) +
              ks * 32 + l4 * 8;
          const float4 fa = *(const float4*)(src);
          const float4 fb = *(const float4*)(src + 4);
          uint4 v;
          v.x = (uint32_t)f2bf_rne(fa.x) | ((uint32_t)f2bf_rne(fa.y) << 16);
          v.y = (uint32_t)f2bf_rne(fa.z) | ((uint32_t)f2bf_rne(fa.w) << 16);
          v.z = (uint32_t)f2bf_rne(fb.x) | ((uint32_t)f2bf_rne(fb.y) << 16);
          v.w = (uint32_t)f2bf_rne(fb.z) | ((uint32_t)f2bf_rne(fb.w) << 16);
          *(uint4*)(ldsA + id * 1024 + (lane << 4)) = v;
        } else {
          async_load16(
              g1 + (size_t)(m0 + mi * 16 + l15) * KP + kbg + ks * 32 + l4 * 8,
              ldsA + id * 1024);
        }
      }
#pragma unroll
      for (int t = 0; t < 4; ++t) {  // B units: id = ks*8 + ni
        const int id = wv * 4 + t;
        const int ni = id & 7, ks = id >> 3;
        async_load16(Bt + (size_t)(n0 + ni * 16 + l15) * KP + kbg + ks * 32 + l4 * 8,
                     ldsB + id * 1024);
      }
      __syncthreads();
#pragma unroll
      for (int ks = 0; ks < 2; ++ks) {
        bf16x8_t Af[4], Bf[2];
#pragma unroll
        for (int a = 0; a < 4; ++a)
          Af[a] = *(const bf16x8_t*)(ldsA + ((ks * 4 + a) << 10) + (lane << 4));
#pragma unroll
        for (int q = 0; q < 2; ++q)
          Bf[q] = *(const bf16x8_t*)(ldsB + ((ks * 8 + wv * 2 + q) << 10) + (lane << 4));
#pragma unroll
        for (int a = 0; a < 4; ++a)
#pragma unroll
          for (int q = 0; q < 2; ++q)
            acc[a][q] = __builtin_amdgcn_mfma_f32_16x16x32_bf16(Af[a], Bf[q],
                                                                acc[a][q], 0, 0, 0);
      }
      __syncthreads();
    }

    float bias[2];
#pragma unroll
    for (int q = 0; q < 2; ++q) {
      const int cc = wv * 32 + q * 16 + l15;
      bias[q] = (nt == 0) ? b1[cc] : ((nt == 1) ? b2[cc] : 0.f);
    }
#pragma unroll
    for (int a = 0; a < 4; ++a) {
      const int rl = a * 16 + l4 * 4;
#pragma unroll
      for (int r = 0; r < 4; ++r) {
        const size_t bi = m0 + rl + r;
#pragma unroll
        for (int q = 0; q < 2; ++q) {
          const int cc = wv * 32 + q * 16 + l15;
          const float x = acc[a][q][r] + bias[q];
          if (nt == 0) {
            const float val = sigf(x);
            f1out[bi * OC + cc] = val;
            if (DUP) g1next[bi * 512 + 128 + cc] = f2bf_rne(val);
          } else if (nt == 1) {
            u[bi * OC + cc] = x;
          } else {
            const int b = (int)(bi >> 8), j = (int)(bi & 255);
            vT[((size_t)b * OC + cc) * NN + j] = x;
          }
        }
      }
    }
  } else {
    // ---- o0 for batch b ----
    constexpr int FIN0 = D0 + 2 * D1;
    constexpr int S = 256 / D1;
    const int b = bid - 48;
    float* const sm = (float*)ldsA;   // reuse LDS: g0 | smx | smn | sval
    float* const g0 = sm;
    float* const smx = sm + 512;
    float* const smn = sm + 768;
    float* const sval = sm + 1024;
    const int cc = tid & (D1 - 1), ss = tid / D1;
    float mx = -1e30f, mn = 1e30f;
    const float* f1b = f1in + (size_t)b * NN * D1;
    for (int j = ss; j < NN; j += S) {
      const float x = f1b[(size_t)j * D1 + cc];
      mx = fmaxf(mx, x); mn = fminf(mn, x);
    }
    smx[tid] = mx; smn[tid] = mn;
    __syncthreads();
    if (ss == 0) {
      for (int s2 = 1; s2 < S; ++s2) {
        mx = fmaxf(mx, smx[cc + s2 * D1]);
        mn = fminf(mn, smn[cc + s2 * D1]);
      }
      g0[D0 + cc] = mx;
      g0[D0 + D1 + cc] = mn;
    }
    if (tid < D0) g0[tid] = f0in[b * D0 + tid];
    __syncthreads();
    if (tid < OC) {
      float acc = b0[tid];
#pragma unroll 8
      for (int k = 0; k < FIN0; ++k) acc += g0[k] * W0[k * OC + tid];
      const float val = sigf(acc);
      f0out[b * OC + tid] = val;
      sval[tid] = val;
    }
    if (DUP) {
      __syncthreads();
      for (int idx = tid; idx < 256 * 128; idx += 256) {
        const int row = idx >> 7, c2 = idx & 127;
        g1next[((size_t)(b * 256 + row)) * 512 + c2] = f2bf_rne(sval[c2]);
      }
    }
  }
}

// ---------------------------------------------------------------------------
// Big order-2 GEMM body (R7 dbuf/counted-vmcnt structure). Epilogue spins on
// done==52 (u/vT producers) -- sg latency hides under the K-loop.
// ---------------------------------------------------------------------------
template <int D2, typename OUT_T, bool REDUCE>
__device__ void gemm2_body(int tile, const __hip_bfloat16* __restrict__ f2,
                           const uint16_t* __restrict__ Wt,
                           const float* __restrict__ u,
                           const float* __restrict__ vT,
                           OUT_T* __restrict__ out, float* __restrict__ r2n,
                           unsigned* done, uint8_t* lds, unsigned* smax,
                           unsigned* smin, int tid) {
  constexpr int K = 2 * D2;
  constexpr int NCH = K / 32;
  constexpr bool BF16OUT = (sizeof(OUT_T) == 2);
  const int jt = tile & 1, i = (tile >> 1) & 255, b = tile >> 9;
  const int j0 = jt * 128;
  const int wv = tid >> 6, lane = tid & 63;
  const int wr = wv >> 1, wc = wv & 1;
  const int l15 = lane & 15, l4 = lane >> 4;

  __syncthreads();  // LDS handoff from previous phase/tile

  const __hip_bfloat16* const A1 = f2 + ((size_t)(b * NN + i) * NN + j0) * D2;
  const __hip_bfloat16* const A2 = f2 + ((size_t)(b * NN + j0) * NN + i) * D2;

  f32x4_t acc[4][4];
#pragma unroll
  for (int a = 0; a < 4; ++a)
#pragma unroll
    for (int q = 0; q < 4; ++q) acc[a][q] = (f32x4_t){0.f, 0.f, 0.f, 0.f};

  auto STAGE = [&](int c, int buf) {
    const int kbg = c * 32;
    uint8_t* const bA = lds + buf * 16384;
    uint8_t* const bW = bA + 8192;
    const bool second = (kbg >= D2);
    const __hip_bfloat16* const Ab = second ? A2 : A1;
    const size_t rstride = second ? (size_t)NN * D2 : (size_t)D2;
    const int kbase = second ? (kbg - D2) : kbg;
#pragma unroll
    for (int t = 0; t < 2; ++t) {
      const int mi = wv * 2 + t;
      async_load16(Ab + (size_t)(mi * 16 + l15) * rstride + kbase + l4 * 8,
                   bA + mi * 1024);
    }
#pragma unroll
    for (int t = 0; t < 2; ++t) {
      const int ni = wv * 2 + t;
      async_load16(Wt + (size_t)(ni * 16 + l15) * K + kbg + l4 * 8,
                   bW + ni * 1024);
    }
  };

  auto COMPUTE = [&](int buf) {
    const uint8_t* const bA = lds + buf * 16384;
    const uint8_t* const bW = bA + 8192;
    bf16x8_t Af[4], Bf[4];
#pragma unroll
    for (int a = 0; a < 4; ++a)
      Af[a] = *(const bf16x8_t*)(bA + ((wr * 4 + a) << 10) + (lane << 4));
#pragma unroll
    for (int q = 0; q < 4; ++q)
      Bf[q] = *(const bf16x8_t*)(bW + ((wc * 4 + q) << 10) + (lane << 4));
#pragma unroll
    for (int a = 0; a < 4; ++a)
#pragma unroll
      for (int q = 0; q < 4; ++q)
        acc[a][q] = __builtin_amdgcn_mfma_f32_16x16x32_bf16(Af[a], Bf[q],
                                                            acc[a][q], 0, 0, 0);
  };

  STAGE(0, 0);
#pragma unroll
  for (int c = 0; c < NCH - 1; ++c) {
    STAGE(c + 1, (c + 1) & 1);
    asm volatile("s_waitcnt vmcnt(4)" ::: "memory");
    __builtin_amdgcn_sched_barrier(0);
    __builtin_amdgcn_s_barrier();
    __builtin_amdgcn_sched_barrier(0);
    COMPUTE(c & 1);
    asm volatile("s_waitcnt lgkmcnt(0)" ::: "memory");
    __builtin_amdgcn_sched_barrier(0);
    __builtin_amdgcn_s_barrier();
    __builtin_amdgcn_sched_barrier(0);
  }
  asm volatile("s_waitcnt vmcnt(0)" ::: "memory");
  __builtin_amdgcn_sched_barrier(0);
  __builtin_amdgcn_s_barrier();
  __builtin_amdgcn_sched_barrier(0);
  COMPUTE((NCH - 1) & 1);
  __syncthreads();  // drain before LDS reuse by epilogue

  wait_done(done, tid);  // u/vT producers finished (hidden under K-loop)

  const size_t bi2 = (size_t)(b * NN + i);
  float uval[4];
#pragma unroll
  for (int q = 0; q < 4; ++q) uval[q] = u[bi2 * OC + wc * 64 + q * 16 + l15];
  const size_t obase = (bi2 * NN + j0) * OC;
  const float* const vTb = vT + (size_t)b * OC * NN;

  if (BF16OUT) {
    if (REDUCE && tid < 128) { smax[tid] = 0u; smin[tid] = 0x3f800000u; }
    __syncthreads();
    float lmx[4] = {0.f, 0.f, 0.f, 0.f};
    float lmn[4] = {1.f, 1.f, 1.f, 1.f};
#pragma unroll
    for (int a = 0; a < 4; ++a) {
      const int rowb = wr * 64 + a * 16 + l4 * 4;
      const int jg = j0 + rowb;
#pragma unroll
      for (int q = 0; q < 4; ++q) {
        const int col = wc * 64 + q * 16 + l15;
        const float4 vq = *(const float4*)(vTb + (size_t)col * NN + jg);
#pragma unroll
        for (int r = 0; r < 4; ++r) {
          const int j = rowb + r;
          const float x = acc[a][q][r] + uval[q] + ((const float*)&vq)[r];
          const float sg = sigf(x);
          *(uint16_t*)(lds + j * 272 + col * 2) = f2bf_rne(sg);
          if (REDUCE && (jg + r) != i) {
            lmx[q] = fmaxf(lmx[q], sg);
            lmn[q] = fminf(lmn[q], sg);
          }
        }
      }
    }
    if (REDUCE) {
#pragma unroll
      for (int q = 0; q < 4; ++q) {
        const int col = wc * 64 + q * 16 + l15;
        atomicMax(&smax[col], __float_as_uint(lmx[q]));
        atomicMin(&smin[col], __float_as_uint(lmn[q]));
      }
    }
    __syncthreads();
    uint16_t* const outp = (uint16_t*)out;
#pragma unroll
    for (int ci = 0; ci < 8; ++ci) {
      const int chunk = ci * 256 + tid;
      const int row = chunk >> 4, off = chunk & 15;
      const uint4 val = *(const uint4*)(lds + row * 272 + off * 16);
      *(uint4*)(outp + obase + (size_t)row * OC + off * 8) = val;
    }
    if (REDUCE && tid < 128) {
      unsigned* const r2u = (unsigned*)r2n;
      atomicMax(&r2u[bi2 * 256 + tid], smax[tid]);
      atomicMin(&r2u[bi2 * 256 + 128 + tid], smin[tid]);
    }
  } else {
    float* const outp = (float*)out;
#pragma unroll
    for (int a = 0; a < 4; ++a) {
      const int rowb = wr * 64 + a * 16 + l4 * 4;
      const int jg = j0 + rowb;
#pragma unroll
      for (int q = 0; q < 4; ++q) {
        const int col = wc * 64 + q * 16 + l15;
        const float4 vq = *(const float4*)(vTb + (size_t)col * NN + jg);
#pragma unroll
        for (int r = 0; r < 4; ++r) {
          const int j = rowb + r;
          const float x = acc[a][q][r] + uval[q] + ((const float*)&vq)[r];
          outp[obase + (size_t)j * OC + col] = sigf(x);
        }
      }
    }
  }
}

// ---------------------------------------------------------------------------
// Megakernel: prep+reduce2 | sg-l0 || gemm2-l0 | sg-l1 || gemm2-l1 |
// sg-l2 || gemm2-l2, with 3 grid barriers and done-flag spins.
// ---------------------------------------------------------------------------
__global__ __launch_bounds__(256, 4) void megakernel(
    Ctrs* C, const float* x0, const float* x1, const float* x2,
    const float* W0_0, const float* b0_0, const float* W1_0, const float* b1_0,
    const float* W2_0, const float* b2_0, const float* W0_1, const float* b0_1,
    const float* W1_1, const float* b1_1, const float* W2_1, const float* b2_1,
    const float* W0_2, const float* b0_2, const float* W1_2, const float* b1_2,
    const float* W2_2, const float* b2_2, uint16_t* Wt0, uint16_t* Wt1,
    uint16_t* Wt2, uint16_t* Bt0, uint16_t* Bt1, uint16_t* Bt2,
    uint16_t* g1bf0, uint16_t* g1bf1, uint16_t* g1bf2, float* r2b, float* r2c,
    float* f0a, float* f0b, float* f1a, float* f1b, float* uu, float* vT,
    uint16_t* x2bf, __hip_bfloat16* f2a, __hip_bfloat16* f2b, float* out_f0,
    float* out_f1, float* out_f2) {
  __shared__ __align__(16) uint8_t lds[34816];
  __shared__ unsigned smax[128], smin[128];
  const int bid = blockIdx.x;
  const int tid = threadIdx.x;

  // ---- P0: prep (4800 units) + reduce2-l0 (1024 units) ----
  for (int p = 0; p < 6; ++p) {
    const int unit = p * GRID + bid;
    if (unit < 4800) {
      prep_unit(unit * 256 + tid, W2_0, W2_1, W2_2, W1_0, W1_1, W1_2, x0, x1,
                Wt0, Wt1, Wt2, Bt0, Bt1, Bt2, g1bf0, r2b, r2c);
    } else if (unit < 5824) {
      reduce2_unit(unit - 4800, x2, g1bf0, x2bf, lds, tid);
    }
    __syncthreads();
  }
  gbar(C, tid);

  // ---- layer 0 ----
  if (bid < 52) {
    sg_body<256, 32, 64, true, false>(bid, g1bf0, Bt0, b1_0, b2_0, f1a, g1bf1,
                                      uu, vT, x0, x1, W0_0, b0_0, f0a, nullptr,
                                      lds, lds + 8192, tid);
    mark_done(&C->done0, tid);
  }
  gemm2_body<64, __hip_bfloat16, true>(bid, (const __hip_bfloat16*)x2bf, Wt0,
                                       uu, vT, f2a, r2b, &C->done0, lds, smax,
                                       smin, tid);
  gemm2_body<64, __hip_bfloat16, true>(bid + GRID, (const __hip_bfloat16*)x2bf,
                                       Wt0, uu, vT, f2a, r2b, &C->done0, lds,
                                       smax, smin, tid);
  gbar(C, tid);

  // ---- layer 1 ----
  if (bid < 52) {
    sg_body<512, 128, 128, true, true>(bid, g1bf1, Bt1, b1_1, b2_1, f1b, g1bf2,
                                       uu, vT, f0a, f1a, W0_1, b0_1, f0b, r2b,
                                       lds, lds + 8192, tid);
    mark_done(&C->done1, tid);
  }
  gemm2_body<128, __hip_bfloat16, true>(bid, f2a, Wt1, uu, vT, f2b, r2c,
                                        &C->done1, lds, smax, smin, tid);
  gemm2_body<128, __hip_bfloat16, true>(bid + GRID, f2a, Wt1, uu, vT, f2b, r2c,
                                        &C->done1, lds, smax, smin, tid);
  gbar(C, tid);

  // ---- layer 2 ----
  if (bid < 52) {
    sg_body<512, 128, 128, false, true>(bid, g1bf2, Bt2, b1_2, b2_2, out_f1,
                                        nullptr, uu, vT, f0b, f1b, W0_2, b0_2,
                                        out_f0, r2c, lds, lds + 8192, tid);
    mark_done(&C->done2, tid);
  }
  gemm2_body<128, float, false>(bid, f2b, Wt2, uu, vT, out_f2, nullptr,
                                &C->done2, lds, smax, smin, tid);
  gemm2_body<128, float, false>(bid + GRID, f2b, Wt2, uu, vT, out_f2, nullptr,
                                &C->done2, lds, smax, smin, tid);
}

// ---------------------------------------------------------------------------
extern "C" void kernel_launch(void* const* d_in, const int* in_sizes, int n_in,
                              void* d_out, int out_size, void* d_ws,
                              size_t ws_size, hipStream_t stream) {
  const float* x0 = (const float*)d_in[0];
  const float* x1 = (const float*)d_in[1];
  const float* x2 = (const float*)d_in[2];
  const float *Wp[3][3], *bp[3][3];
  for (int l = 0; l < 3; ++l)
    for (int o = 0; o < 3; ++o) {
      Wp[l][o] = (const float*)d_in[3 + l * 6 + o * 2];
      bp[l][o] = (const float*)d_in[3 + l * 6 + o * 2 + 1];
    }

  const size_t F2E = (size_t)NB * NN * NN * OC;
  const size_t X2E = (size_t)NB * NN * NN * 64;

  uint8_t* ws = (uint8_t*)d_ws;
  size_t off = 0;
  auto carve = [&](size_t bytes) -> uint8_t* {
    uint8_t* p = ws + off;
    off += (bytes + 255) & ~(size_t)255;
    return p;
  };
  Ctrs* ctrs = (Ctrs*)carve(256);
  float* f0a = (float*)carve((size_t)NB * OC * 4);
  float* f0b = (float*)carve((size_t)NB * OC * 4);
  float* f1a = (float*)carve((size_t)NB * NN * OC * 4);
  float* f1b = (float*)carve((size_t)NB * NN * OC * 4);
  float* r2b = (float*)carve((size_t)NB * NN * 256 * 4);
  float* r2c = (float*)carve((size_t)NB * NN * 256 * 4);
  float* uu  = (float*)carve((size_t)NB * NN * OC * 4);
  float* vT  = (float*)carve((size_t)NB * OC * NN * 4);
  uint16_t* Wt0 = (uint16_t*)carve((size_t)OC * 128 * 2);
  uint16_t* Wt1 = (uint16_t*)carve((size_t)OC * 256 * 2);
  uint16_t* Wt2 = (uint16_t*)carve((size_t)OC * 256 * 2);
  uint16_t* Bt0 = (uint16_t*)carve((size_t)384 * 256 * 2);
  uint16_t* Bt1 = (uint16_t*)carve((size_t)384 * 512 * 2);
  uint16_t* Bt2 = (uint16_t*)carve((size_t)384 * 512 * 2);
  uint16_t* g1bf0 = (uint16_t*)carve((size_t)NB * NN * 256 * 2);
  uint16_t* g1bf1 = (uint16_t*)carve((size_t)NB * NN * 512 * 2);
  uint16_t* g1bf2 = (uint16_t*)carve((size_t)NB * NN * 512 * 2);
  __hip_bfloat16* f2a = (__hip_bfloat16*)carve(F2E * 2);

  __hip_bfloat16* f2b;
  uint16_t* x2bf;
  if (ws_size >= off + F2E * 2) {
    f2b = (__hip_bfloat16*)carve(F2E * 2);
    x2bf = (uint16_t*)f2b;  // aliases f2b; dead before f2b becomes live
  } else {
    f2b = (__hip_bfloat16*)d_in[2];  // x2 fully consumed in layer 0
    x2bf = (uint16_t*)carve(X2E * 2);
  }

  float* out_f0 = (float*)d_out;
  float* out_f1 = out_f0 + (size_t)NB * OC;
  float* out_f2 = out_f1 + (size_t)NB * NN * OC;

  hipMemsetAsync(ctrs, 0, sizeof(Ctrs), stream);
  megakernel<<<GRID, 256, 0, stream>>>(
      ctrs, x0, x1, x2, Wp[0][0], bp[0][0], Wp[0][1], bp[0][1], Wp[0][2],
      bp[0][2], Wp[1][0], bp[1][0], Wp[1][1], bp[1][1], Wp[1][2], bp[1][2],
      Wp[2][0], bp[2][0], Wp[2][1], bp[2][1], Wp[2][2], bp[2][2], Wt0, Wt1,
      Wt2, Bt0, Bt1, Bt2, g1bf0, g1bf1, g1bf2, r2b, r2c, f0a, f0b, f1a, f1b,
      uu, vT, x2bf, f2a, f2b, out_f0, out_f1, out_f2);
}